// Round 11
// baseline (78.334 us; speedup 1.0000x reference)
//
#include <hip/hip_runtime.h>

#define LEAK 0.01f

typedef float v2f __attribute__((ext_vector_type(2)));
typedef _Float16 h2 __attribute__((ext_vector_type(2)));

// Problem constants
constexpr int H = 1024, W = 1024, NIMG = 4;
constexpr int GC = 12, GD = 12, GH = 16, GW = 16;
constexpr int NZ = GD - 1;           // 11 z0 values (z-pairs)
constexpr int CELLE = NZ * GC;       // 132 half2 per (y,x) grid cell
constexpr int CF4 = 33;              // float4 chunks per cell (132 h2 = 528 B)

// Tiling: 256 threads (64x4), each thread does 4 pixels along x -> 256x4 tile
constexpr int PX = 4;
constexpr int BX = 64, BY = 4;
constexpr int TILE_W = BX * PX;      // 256
constexpr int XS = 6;                // x-cell footprint of a 256-wide tile
constexpr int SGN = BY * XS * CF4;   // 792 float4 of sgrid staging

// fp16 fullres LDS slab: h2 p <-> global x pair {wb-8+2p, wb-7+2p}
constexpr int IMROWS = BY + 2;       // 6 rows: hb-1 .. hb+4
constexpr int IMW2   = 136;          // h2 per row (134 needed, +2 pad)
constexpr int IMCH2  = IMROWS * IMW2;
constexpr int IMCHUNK = 67;          // float4 chunks per (ch,row): gx = wb-8 .. wb+259

static __device__ __forceinline__ h2 bch2(float f) {
    return __builtin_bit_cast(h2, f);
}
static __device__ __forceinline__ float bcf(h2 v) {
    return __builtin_bit_cast(float, v);
}
// cvt_pkrtz returns __fp16x2; bit-cast to our h2 (_Float16x2) — same bits.
static __device__ __forceinline__ h2 pkrtz(float a, float b) {
    return __builtin_bit_cast(h2, __builtin_amdgcn_cvt_pkrtz(a, b));
}

static __device__ __forceinline__ float fdot2f(h2 a, h2 b, float c) {
#if __has_builtin(__builtin_amdgcn_fdot2)
    return __builtin_amdgcn_fdot2(a, b, c, false);
#else
    return (float)a.x * (float)b.x + (float)a.y * (float)b.y + c;
#endif
}

// ---- pre-kernel: build z-pair half2 table in ws ----
// table layout: [n][y*16+x][z0*12+c]  (132 half2 = 528 B contiguous per cell)
__global__ __launch_bounds__(256) void pairgen(const float* __restrict__ grid,
                                               h2* __restrict__ table) {
    const int n  = blockIdx.x / NZ;
    const int z0 = blockIdx.x % NZ;
    const int yx = threadIdx.x;      // 0..255, coalesced over lanes
    const float* src = grid + (size_t)n * GC * GD * GH * GW + yx;
    h2* dst = table + ((size_t)n * 256 + yx) * CELLE + z0 * GC;
    #pragma unroll
    for (int c = 0; c < GC; ++c) {
        float a = src[(c * GD + z0) * 256];
        float b = src[(c * GD + z0 + 1) * 256];
        dst[c] = pkrtz(a, b);
    }
}

__global__ __launch_bounds__(256, 6) void hdrnet_fused(
    const float* __restrict__ grid,   // (N,12,12,16,16)
    const float* __restrict__ full,   // (N,3,H,W)
    const float* __restrict__ w1,     // (3,3,1,1)
    const float* __restrict__ w3,     // (3,3,3,3)
    const float* __restrict__ b3,     // (3)
    const float* __restrict__ bias,   // (1)
    const h2* __restrict__ table,     // pair table or nullptr
    float* __restrict__ out)          // (N,3,H,W)
{
    __shared__ __align__(16) h2 simgh[3 * IMCH2];        // 9792 B, fp16 image
    __shared__ __align__(16) h2 sgrid[BY * XS * CELLE];  // 12672 B

    const int n  = blockIdx.z;
    const int wb = blockIdx.x * TILE_W;
    const int hb = blockIdx.y * BY;

    const float scale = 15.0f / 1023.0f;
    const int xlo = (int)(wb * scale);

    const int tid = threadIdx.y * BX + threadIdx.x;
    const size_t plane = (size_t)H * W;
    const float* fn = full + (size_t)n * 3 * plane;

    // ---- issue table loads FIRST (oldest in vmcnt queue; latency hidden
    //      under the image staging loop) ----
    float4 tA[4], tB[4];
    const bool ttail = (tid < SGN - 768);   // 24 threads do a 4th element
    if (table) {
        const float4* tsrc = (const float4*)(table + (size_t)n * 256 * CELLE);
        #pragma unroll
        for (int it = 0; it < 3; ++it) {
            int e  = tid + 256 * it;
            int r  = e / (XS * CF4);
            int t2 = e - r * (XS * CF4);
            int lx = t2 / CF4, q = t2 - lx * CF4;
            int y0 = min((int)((float)(hb + r) * scale), GH - 2);
            int xi = min(xlo + lx, GW - 1);
            tA[it] = tsrc[(y0 * GW + xi) * CF4 + q];
            tB[it] = tsrc[((y0 + 1) * GW + xi) * CF4 + q];
        }
        if (ttail) {
            int e  = 768 + tid;
            int r  = e / (XS * CF4);
            int t2 = e - r * (XS * CF4);
            int lx = t2 / CF4, q = t2 - lx * CF4;
            int y0 = min((int)((float)(hb + r) * scale), GH - 2);
            int xi = min(xlo + lx, GW - 1);
            tA[3] = tsrc[(y0 * GW + xi) * CF4 + q];
            tB[3] = tsrc[((y0 + 1) * GW + xi) * CF4 + q];
        }
    }

    // ---- stage fullres tile into LDS as fp16 pairs (coalesced, zero-pad) ----
    for (int e = tid; e < 3 * IMROWS * IMCHUNK; e += BX * BY) {   // 1206 chunks
        int ch = e / (IMROWS * IMCHUNK);
        int t  = e - ch * (IMROWS * IMCHUNK);
        int r  = t / IMCHUNK, m = t - r * IMCHUNK;
        int yy = hb + r - 1;
        int gx = wb - 8 + 4 * m;
        float4 v = (float4){0.0f, 0.0f, 0.0f, 0.0f};
        if ((unsigned)yy < (unsigned)H && (unsigned)gx < (unsigned)W)
            v = *(const float4*)(fn + (size_t)ch * plane + (size_t)yy * W + gx);
        *(float2*)&simgh[(ch * IMROWS + r) * IMW2 + 2 * m] =
            (float2){bcf(pkrtz(v.x, v.y)), bcf(pkrtz(v.z, v.w))};
    }

    // ---- sgrid: y-lerp from registers, write LDS (pre-barrier; no simgh dep) ----
    if (table) {
        float4* sdst = (float4*)sgrid;
        #pragma unroll
        for (int it = 0; it < 4; ++it) {
            if (it == 3 && !ttail) break;
            int e = (it == 3) ? (768 + tid) : (tid + 256 * it);
            int r = e / (XS * CF4);
            float fy = (float)(hb + r) * scale;
            float ty = fy - (float)min((int)fy, GH - 2);
            _Float16 t1 = (_Float16)ty, t0 = (_Float16)(1.0f - ty);
            h2 w0v = (h2){t0, t0}, w1v = (h2){t1, t1};
            float4 A = tA[it], B = tB[it], R;
            R.x = bcf(bch2(A.x) * w0v + bch2(B.x) * w1v);
            R.y = bcf(bch2(A.y) * w0v + bch2(B.y) * w1v);
            R.z = bcf(bch2(A.z) * w0v + bch2(B.z) * w1v);
            R.w = bcf(bch2(A.w) * w0v + bch2(B.w) * w1v);
            sdst[e] = R;
        }
    } else {
        const float* gnn = grid + (size_t)n * GC * GD * GH * GW;
        for (int e = tid; e < BY * XS * CELLE; e += BX * BY) {
            int r  = e / (XS * CELLE);
            int t  = e - r * (XS * CELLE);
            int lx = t / CELLE, u = t - lx * CELLE;
            int z0 = u / GC, c = u - z0 * GC;
            float fy = (float)(hb + r) * scale;
            int y0 = min((int)fy, GH - 2);
            float ty = fy - (float)y0;
            int xi = min(xlo + lx, GW - 1);
            const float* gp = gnn + ((c * GD + z0) * GH + y0) * GW + xi;
            float a0 = gp[0],  a1 = gp[256];
            float b0 = gp[16], b1 = gp[272];
            sgrid[e] = pkrtz(fmaf(b0 - a0, ty, a0), fmaf(b1 - a1, ty, a1));
        }
    }
    __syncthreads();   // single barrier: simgh AND sgrid both ready

    const int h  = hb + threadIdx.y;
    const int w0 = wb + threadIdx.x * PX;

    // ---- weights to registers ----
    float w1c[3][3];
    #pragma unroll
    for (int o = 0; o < 3; ++o)
        #pragma unroll
        for (int i = 0; i < 3; ++i)
            w1c[o][i] = w1[o * 3 + i];
    const float biasv = bias[0];

    // ---- 3x3 conv over 3 ch for 4 pixels, rows from fp16 LDS (fp32 math) ----
    v2f a3p[3][2];
    #pragma unroll
    for (int o = 0; o < 3; ++o) {
        float b = b3[o];
        a3p[o][0] = (v2f){b, b};
        a3p[o][1] = (v2f){b, b};
    }
    float rgb[3][PX];

    #pragma unroll
    for (int i = 0; i < 3; ++i) {
        #pragma unroll
        for (int dy = 0; dy < 3; ++dy) {
            // h2 window: halo pair at p=2tx+3 (.y = w0-1), main 4 h2 = w0..w0+7
            const h2* rowp = &simgh[(i * IMROWS + threadIdx.y + dy) * IMW2
                                    + 2 * threadIdx.x];
            h2 hh = rowp[3];
            float2 m01 = *(const float2*)(rowp + 4);
            float2 m23 = *(const float2*)(rowp + 6);
            h2 q0 = bch2(m01.x), q1 = bch2(m01.y);
            h2 q2 = bch2(m23.x), q3 = bch2(m23.y);
            float row[8];
            row[0] = (float)hh.y;
            row[1] = (float)q0.x; row[2] = (float)q0.y;
            row[3] = (float)q1.x; row[4] = (float)q1.y;
            row[5] = (float)q2.x; row[6] = (float)q2.y;
            row[7] = (float)q3.x;
            if (dy == 1) {
                #pragma unroll
                for (int j = 0; j < PX; ++j) rgb[i][j] = row[1 + j];
            }
            #pragma unroll
            for (int o = 0; o < 3; ++o) {
                const float* kp = w3 + ((o * 3 + i) * 3 + dy) * 3;
                #pragma unroll
                for (int t = 0; t < 3; ++t) {
                    const float kt = kp[t];
                    v2f kv = (v2f){kt, kt};
                    a3p[o][0] = __builtin_elementwise_fma(
                        kv, (v2f){row[t], row[t + 1]}, a3p[o][0]);
                    a3p[o][1] = __builtin_elementwise_fma(
                        kv, (v2f){row[t + 2], row[t + 3]}, a3p[o][1]);
                }
            }
        }
    }

    // ---- guide for all 4 px ----
    float gq[PX];
    #pragma unroll
    for (int j = 0; j < PX; ++j) {
        float gacc = 0.0f;
        #pragma unroll
        for (int o = 0; o < 3; ++o) {
            float x1 = fmaf(w1c[o][0], rgb[0][j],
                       fmaf(w1c[o][1], rgb[1][j], w1c[o][2] * rgb[2][j]));
            x1 = (x1 > 0.0f) ? x1 : LEAK * x1;
            float x3 = a3p[o][j >> 1][j & 1];
            x3 = (x3 > 0.0f) ? x3 : LEAK * x3;
            gacc += x1 + x3;
        }
        float g = fmaf(gacc, (1.0f / 3.0f), biasv);
        gq[j] = fminf(fmaxf(g, 0.0f), 1.0f);
    }

    const int srow = threadIdx.y * XS;       // this thread-row's cell base
    const float4* sg4 = (const float4*)sgrid;

    float4 ov0, ov1, ov2;
    float* ov0p = &ov0.x; float* ov1p = &ov1.x; float* ov2p = &ov2.x;

    // ---- slice+apply, pixel-PAIR batched (12 b128 in flight per pair) ----
    #pragma unroll
    for (int jp = 0; jp < 2; ++jp) {
        const int ja = 2 * jp, jb = ja + 1;

        // coords px a
        float fxa = (float)(w0 + ja) * scale;
        int   x0a = min((int)fxa, GW - 2);
        float txa = fxa - (float)x0a;
        float fza = gq[ja] * 11.0f;
        int   z0a = min((int)fza, GD - 2);
        float tza = fza - (float)z0a;
        h2 hza = pkrtz(1.0f - tza, tza);
        _Float16 ax0 = (_Float16)(1.0f - txa), ax1 = (_Float16)txa;
        h2 wAa = hza * (h2){ax0, ax0};
        h2 wBa = hza * (h2){ax1, ax1};
        const float4* pAa = sg4 + (srow + x0a - xlo) * CF4 + z0a * 3;
        const float4* pBa = pAa + CF4;

        // coords px b
        float fxb = (float)(w0 + jb) * scale;
        int   x0b = min((int)fxb, GW - 2);
        float txb = fxb - (float)x0b;
        float fzb = gq[jb] * 11.0f;
        int   z0b = min((int)fzb, GD - 2);
        float tzb = fzb - (float)z0b;
        h2 hzb = pkrtz(1.0f - tzb, tzb);
        _Float16 bx0 = (_Float16)(1.0f - txb), bx1 = (_Float16)txb;
        h2 wAb = hzb * (h2){bx0, bx0};
        h2 wBb = hzb * (h2){bx1, bx1};
        const float4* pAb = sg4 + (srow + x0b - xlo) * CF4 + z0b * 3;
        const float4* pBb = pAb + CF4;

        // issue all 12 LDS reads for the pair
        float4 Aa0 = pAa[0], Aa1 = pAa[1], Aa2 = pAa[2];
        float4 Ba0 = pBa[0], Ba1 = pBa[1], Ba2 = pBa[2];
        float4 Ab0 = pAb[0], Ab1 = pAb[1], Ab2 = pAb[2];
        float4 Bb0 = pBb[0], Bb1 = pBb[1], Bb2 = pBb[2];

        float ca[12], cb[12];
        ca[0]  = fdot2f(wAa, bch2(Aa0.x), fdot2f(wBa, bch2(Ba0.x), 0.0f));
        ca[1]  = fdot2f(wAa, bch2(Aa0.y), fdot2f(wBa, bch2(Ba0.y), 0.0f));
        ca[2]  = fdot2f(wAa, bch2(Aa0.z), fdot2f(wBa, bch2(Ba0.z), 0.0f));
        ca[3]  = fdot2f(wAa, bch2(Aa0.w), fdot2f(wBa, bch2(Ba0.w), 0.0f));
        ca[4]  = fdot2f(wAa, bch2(Aa1.x), fdot2f(wBa, bch2(Ba1.x), 0.0f));
        ca[5]  = fdot2f(wAa, bch2(Aa1.y), fdot2f(wBa, bch2(Ba1.y), 0.0f));
        ca[6]  = fdot2f(wAa, bch2(Aa1.z), fdot2f(wBa, bch2(Ba1.z), 0.0f));
        ca[7]  = fdot2f(wAa, bch2(Aa1.w), fdot2f(wBa, bch2(Ba1.w), 0.0f));
        ca[8]  = fdot2f(wAa, bch2(Aa2.x), fdot2f(wBa, bch2(Ba2.x), 0.0f));
        ca[9]  = fdot2f(wAa, bch2(Aa2.y), fdot2f(wBa, bch2(Ba2.y), 0.0f));
        ca[10] = fdot2f(wAa, bch2(Aa2.z), fdot2f(wBa, bch2(Ba2.z), 0.0f));
        ca[11] = fdot2f(wAa, bch2(Aa2.w), fdot2f(wBa, bch2(Ba2.w), 0.0f));

        cb[0]  = fdot2f(wAb, bch2(Ab0.x), fdot2f(wBb, bch2(Bb0.x), 0.0f));
        cb[1]  = fdot2f(wAb, bch2(Ab0.y), fdot2f(wBb, bch2(Bb0.y), 0.0f));
        cb[2]  = fdot2f(wAb, bch2(Ab0.z), fdot2f(wBb, bch2(Bb0.z), 0.0f));
        cb[3]  = fdot2f(wAb, bch2(Ab0.w), fdot2f(wBb, bch2(Bb0.w), 0.0f));
        cb[4]  = fdot2f(wAb, bch2(Ab1.x), fdot2f(wBb, bch2(Bb1.x), 0.0f));
        cb[5]  = fdot2f(wAb, bch2(Ab1.y), fdot2f(wBb, bch2(Bb1.y), 0.0f));
        cb[6]  = fdot2f(wAb, bch2(Ab1.z), fdot2f(wBb, bch2(Bb1.z), 0.0f));
        cb[7]  = fdot2f(wAb, bch2(Ab1.w), fdot2f(wBb, bch2(Bb1.w), 0.0f));
        cb[8]  = fdot2f(wAb, bch2(Ab2.x), fdot2f(wBb, bch2(Bb2.x), 0.0f));
        cb[9]  = fdot2f(wAb, bch2(Ab2.y), fdot2f(wBb, bch2(Bb2.y), 0.0f));
        cb[10] = fdot2f(wAb, bch2(Ab2.z), fdot2f(wBb, bch2(Bb2.z), 0.0f));
        cb[11] = fdot2f(wAb, bch2(Ab2.w), fdot2f(wBb, bch2(Bb2.w), 0.0f));

        // apply
        {
            const float r = rgb[0][ja], gg = rgb[1][ja], b = rgb[2][ja];
            ov0p[ja] = fmaf(ca[0], r, fmaf(ca[1],  gg, fmaf(ca[2],  b, ca[3])));
            ov1p[ja] = fmaf(ca[4], r, fmaf(ca[5],  gg, fmaf(ca[6],  b, ca[7])));
            ov2p[ja] = fmaf(ca[8], r, fmaf(ca[9],  gg, fmaf(ca[10], b, ca[11])));
        }
        {
            const float r = rgb[0][jb], gg = rgb[1][jb], b = rgb[2][jb];
            ov0p[jb] = fmaf(cb[0], r, fmaf(cb[1],  gg, fmaf(cb[2],  b, cb[3])));
            ov1p[jb] = fmaf(cb[4], r, fmaf(cb[5],  gg, fmaf(cb[6],  b, cb[7])));
            ov2p[jb] = fmaf(cb[8], r, fmaf(cb[9],  gg, fmaf(cb[10], b, cb[11])));
        }
    }

    // ---- coalesced float4 stores ----
    float* ob = out + (size_t)n * 3 * plane + (size_t)h * W + w0;
    *(float4*)(ob)             = ov0;
    *(float4*)(ob + plane)     = ov1;
    *(float4*)(ob + 2 * plane) = ov2;
}

extern "C" void kernel_launch(void* const* d_in, const int* in_sizes, int n_in,
                              void* d_out, int out_size, void* d_ws, size_t ws_size,
                              hipStream_t stream) {
    const float* grid_p = (const float*)d_in[0];
    const float* full_p = (const float*)d_in[1];
    const float* w1_p   = (const float*)d_in[2];
    const float* w3_p   = (const float*)d_in[3];
    const float* b3_p   = (const float*)d_in[4];
    const float* bias_p = (const float*)d_in[5];
    float* out_p = (float*)d_out;

    const size_t tbytes = (size_t)NIMG * 256 * CELLE * sizeof(h2);  // 540,672 B
    h2* table = (d_ws && ws_size >= tbytes) ? (h2*)d_ws : nullptr;

    if (table) {
        hipLaunchKernelGGL(pairgen, dim3(NIMG * NZ), dim3(256), 0, stream,
                           grid_p, table);
    }

    dim3 block(BX, BY, 1);
    dim3 grid_dim(W / TILE_W, H / BY, NIMG);
    hipLaunchKernelGGL(hdrnet_fused, grid_dim, block, 0, stream,
                       grid_p, full_p, w1_p, w3_p, b3_p, bias_p, table, out_p);
}

// Round 12
// 49.045 us; speedup vs baseline: 1.5972x; 1.5972x over previous
//
#include <hip/hip_runtime.h>

#define LEAK 0.01f

typedef float v2f __attribute__((ext_vector_type(2)));
typedef _Float16 h2 __attribute__((ext_vector_type(2)));

// Problem constants
constexpr int H = 1024, W = 1024, NIMG = 4;
constexpr int GC = 12, GD = 12, GH = 16, GW = 16;
constexpr int NZ = GD - 1;           // 11 z0 values (z-pairs)
constexpr int CELLE = NZ * GC;       // 132 half2 per (y,x) grid cell
constexpr int CF4 = 33;              // float4 chunks per cell (132 h2 = 528 B)

// Tiling: 256 threads (64x4), each thread does 4 pixels along x -> 256x4 tile
constexpr int PX = 4;
constexpr int BX = 64, BY = 4;
constexpr int TILE_W = BX * PX;      // 256
constexpr int XS = 6;                // x-cell footprint of a 256-wide tile
constexpr int SGN = BY * XS * CF4;   // 792 float4 of sgrid staging

// fp16 fullres LDS slab: h2 p <-> global x pair {wb-8+2p, wb-7+2p}
constexpr int IMROWS = BY + 2;       // 6 rows: hb-1 .. hb+4
constexpr int IMW2   = 136;          // h2 per row (134 needed, +2 pad)
constexpr int IMCH2  = IMROWS * IMW2;
constexpr int IMCHUNK = 67;          // float4 chunks per (ch,row): gx = wb-8 .. wb+259

static __device__ __forceinline__ h2 bch2(float f) {
    return __builtin_bit_cast(h2, f);
}
static __device__ __forceinline__ float bcf(h2 v) {
    return __builtin_bit_cast(float, v);
}
// cvt_pkrtz returns __fp16x2; bit-cast to our h2 (_Float16x2) — same bits.
static __device__ __forceinline__ h2 pkrtz(float a, float b) {
    return __builtin_bit_cast(h2, __builtin_amdgcn_cvt_pkrtz(a, b));
}

static __device__ __forceinline__ float fdot2f(h2 a, h2 b, float c) {
#if __has_builtin(__builtin_amdgcn_fdot2)
    return __builtin_amdgcn_fdot2(a, b, c, false);
#else
    return (float)a.x * (float)b.x + (float)a.y * (float)b.y + c;
#endif
}

// ---- pre-kernel: build z-pair half2 table in ws ----
// table layout: [n][y*16+x][z0*12+c]  (132 half2 = 528 B contiguous per cell)
__global__ __launch_bounds__(256) void pairgen(const float* __restrict__ grid,
                                               h2* __restrict__ table) {
    const int n  = blockIdx.x / NZ;
    const int z0 = blockIdx.x % NZ;
    const int yx = threadIdx.x;      // 0..255, coalesced over lanes
    const float* src = grid + (size_t)n * GC * GD * GH * GW + yx;
    h2* dst = table + ((size_t)n * 256 + yx) * CELLE + z0 * GC;
    #pragma unroll
    for (int c = 0; c < GC; ++c) {
        float a = src[(c * GD + z0) * 256];
        float b = src[(c * GD + z0 + 1) * 256];
        dst[c] = pkrtz(a, b);
    }
}

__global__ __launch_bounds__(256, 6) void hdrnet_fused(
    const float* __restrict__ grid,   // (N,12,12,16,16)
    const float* __restrict__ full,   // (N,3,H,W)
    const float* __restrict__ w1,     // (3,3,1,1)
    const float* __restrict__ w3,     // (3,3,3,3)
    const float* __restrict__ b3,     // (3)
    const float* __restrict__ bias,   // (1)
    const h2* __restrict__ table,     // pair table or nullptr
    float* __restrict__ out)          // (N,3,H,W)
{
    __shared__ __align__(16) h2 simgh[3 * IMCH2];        // 9792 B, fp16 image
    __shared__ __align__(16) h2 sgrid[BY * XS * CELLE];  // 12672 B

    const int n  = blockIdx.z;
    const int wb = blockIdx.x * TILE_W;
    const int hb = blockIdx.y * BY;

    const float scale = 15.0f / 1023.0f;
    const int xlo = (int)(wb * scale);

    const int tid = threadIdx.y * BX + threadIdx.x;
    const size_t plane = (size_t)H * W;
    const float* fn = full + (size_t)n * 3 * plane;

    // ---- issue table loads FIRST (oldest in vmcnt queue; latency hidden
    //      under the image staging loop) ----
    float4 tA[4], tB[4];
    const bool ttail = (tid < SGN - 768);   // 24 threads do a 4th element
    if (table) {
        const float4* tsrc = (const float4*)(table + (size_t)n * 256 * CELLE);
        #pragma unroll
        for (int it = 0; it < 3; ++it) {
            int e  = tid + 256 * it;
            int r  = e / (XS * CF4);
            int t2 = e - r * (XS * CF4);
            int lx = t2 / CF4, q = t2 - lx * CF4;
            int y0 = min((int)((float)(hb + r) * scale), GH - 2);
            int xi = min(xlo + lx, GW - 1);
            tA[it] = tsrc[(y0 * GW + xi) * CF4 + q];
            tB[it] = tsrc[((y0 + 1) * GW + xi) * CF4 + q];
        }
        if (ttail) {
            int e  = 768 + tid;
            int r  = e / (XS * CF4);
            int t2 = e - r * (XS * CF4);
            int lx = t2 / CF4, q = t2 - lx * CF4;
            int y0 = min((int)((float)(hb + r) * scale), GH - 2);
            int xi = min(xlo + lx, GW - 1);
            tA[3] = tsrc[(y0 * GW + xi) * CF4 + q];
            tB[3] = tsrc[((y0 + 1) * GW + xi) * CF4 + q];
        }
    }

    // ---- stage fullres tile into LDS as fp16 pairs (coalesced, zero-pad) ----
    for (int e = tid; e < 3 * IMROWS * IMCHUNK; e += BX * BY) {   // 1206 chunks
        int ch = e / (IMROWS * IMCHUNK);
        int t  = e - ch * (IMROWS * IMCHUNK);
        int r  = t / IMCHUNK, m = t - r * IMCHUNK;
        int yy = hb + r - 1;
        int gx = wb - 8 + 4 * m;
        float4 v = (float4){0.0f, 0.0f, 0.0f, 0.0f};
        if ((unsigned)yy < (unsigned)H && (unsigned)gx < (unsigned)W)
            v = *(const float4*)(fn + (size_t)ch * plane + (size_t)yy * W + gx);
        *(float2*)&simgh[(ch * IMROWS + r) * IMW2 + 2 * m] =
            (float2){bcf(pkrtz(v.x, v.y)), bcf(pkrtz(v.z, v.w))};
    }

    // ---- sgrid: y-lerp from registers, write LDS (pre-barrier; no simgh dep) ----
    if (table) {
        float4* sdst = (float4*)sgrid;
        #pragma unroll
        for (int it = 0; it < 4; ++it) {
            if (it == 3 && !ttail) break;
            int e = (it == 3) ? (768 + tid) : (tid + 256 * it);
            int r = e / (XS * CF4);
            float fy = (float)(hb + r) * scale;
            float ty = fy - (float)min((int)fy, GH - 2);
            _Float16 t1 = (_Float16)ty, t0 = (_Float16)(1.0f - ty);
            h2 w0v = (h2){t0, t0}, w1v = (h2){t1, t1};
            float4 A = tA[it], B = tB[it], R;
            R.x = bcf(bch2(A.x) * w0v + bch2(B.x) * w1v);
            R.y = bcf(bch2(A.y) * w0v + bch2(B.y) * w1v);
            R.z = bcf(bch2(A.z) * w0v + bch2(B.z) * w1v);
            R.w = bcf(bch2(A.w) * w0v + bch2(B.w) * w1v);
            sdst[e] = R;
        }
    } else {
        const float* gnn = grid + (size_t)n * GC * GD * GH * GW;
        for (int e = tid; e < BY * XS * CELLE; e += BX * BY) {
            int r  = e / (XS * CELLE);
            int t  = e - r * (XS * CELLE);
            int lx = t / CELLE, u = t - lx * CELLE;
            int z0 = u / GC, c = u - z0 * GC;
            float fy = (float)(hb + r) * scale;
            int y0 = min((int)fy, GH - 2);
            float ty = fy - (float)y0;
            int xi = min(xlo + lx, GW - 1);
            const float* gp = gnn + ((c * GD + z0) * GH + y0) * GW + xi;
            float a0 = gp[0],  a1 = gp[256];
            float b0 = gp[16], b1 = gp[272];
            sgrid[e] = pkrtz(fmaf(b0 - a0, ty, a0), fmaf(b1 - a1, ty, a1));
        }
    }
    __syncthreads();   // single barrier: simgh AND sgrid both ready

    const int h  = hb + threadIdx.y;
    const int w0 = wb + threadIdx.x * PX;

    // ---- weights to registers ----
    float w1c[3][3];
    #pragma unroll
    for (int o = 0; o < 3; ++o)
        #pragma unroll
        for (int i = 0; i < 3; ++i)
            w1c[o][i] = w1[o * 3 + i];
    const float biasv = bias[0];

    // ---- 3x3 conv over 3 ch for 4 pixels, rows from fp16 LDS (fp32 math) ----
    v2f a3p[3][2];
    #pragma unroll
    for (int o = 0; o < 3; ++o) {
        float b = b3[o];
        a3p[o][0] = (v2f){b, b};
        a3p[o][1] = (v2f){b, b};
    }
    float rgb[3][PX];

    #pragma unroll
    for (int i = 0; i < 3; ++i) {
        #pragma unroll
        for (int dy = 0; dy < 3; ++dy) {
            // h2 window: halo pair at p=2tx+3 (.y = w0-1), main 4 h2 = w0..w0+7
            const h2* rowp = &simgh[(i * IMROWS + threadIdx.y + dy) * IMW2
                                    + 2 * threadIdx.x];
            h2 hh = rowp[3];
            float2 m01 = *(const float2*)(rowp + 4);
            float2 m23 = *(const float2*)(rowp + 6);
            h2 q0 = bch2(m01.x), q1 = bch2(m01.y);
            h2 q2 = bch2(m23.x), q3 = bch2(m23.y);
            float row[8];
            row[0] = (float)hh.y;
            row[1] = (float)q0.x; row[2] = (float)q0.y;
            row[3] = (float)q1.x; row[4] = (float)q1.y;
            row[5] = (float)q2.x; row[6] = (float)q2.y;
            row[7] = (float)q3.x;
            if (dy == 1) {
                #pragma unroll
                for (int j = 0; j < PX; ++j) rgb[i][j] = row[1 + j];
            }
            #pragma unroll
            for (int o = 0; o < 3; ++o) {
                const float* kp = w3 + ((o * 3 + i) * 3 + dy) * 3;
                #pragma unroll
                for (int t = 0; t < 3; ++t) {
                    const float kt = kp[t];
                    v2f kv = (v2f){kt, kt};
                    a3p[o][0] = __builtin_elementwise_fma(
                        kv, (v2f){row[t], row[t + 1]}, a3p[o][0]);
                    a3p[o][1] = __builtin_elementwise_fma(
                        kv, (v2f){row[t + 2], row[t + 3]}, a3p[o][1]);
                }
            }
        }
    }

    const int srow = threadIdx.y * XS;       // this thread-row's cell base
    const float4* sg4 = (const float4*)sgrid;

    float4 ov0, ov1, ov2;
    float* ov0p = &ov0.x; float* ov1p = &ov1.x; float* ov2p = &ov2.x;

    #pragma unroll
    for (int j = 0; j < PX; ++j) {
        // guide
        float gacc = 0.0f;
        #pragma unroll
        for (int o = 0; o < 3; ++o) {
            float x1 = fmaf(w1c[o][0], rgb[0][j],
                       fmaf(w1c[o][1], rgb[1][j], w1c[o][2] * rgb[2][j]));
            x1 = (x1 > 0.0f) ? x1 : LEAK * x1;
            float x3 = a3p[o][j >> 1][j & 1];
            x3 = (x3 > 0.0f) ? x3 : LEAK * x3;
            gacc += x1 + x3;
        }
        float g = fmaf(gacc, (1.0f / 3.0f), biasv);
        g = fminf(fmaxf(g, 0.0f), 1.0f);

        // slice coords (y already folded into LDS)
        float fx = (float)(w0 + j) * scale;
        int x0 = (int)fx;
        x0 = min(x0, GW - 2);
        float tx = fx - (float)x0;
        const int lxr = x0 - xlo;      // 0..4

        float fz = g * 11.0f;
        int z0 = (int)fz;
        z0 = min(z0, GD - 2);
        float tz = fz - (float)z0;
        h2 hz = pkrtz(1.0f - tz, tz);
        _Float16 hx0 = (_Float16)(1.0f - tx), hx1 = (_Float16)tx;
        h2 wA = hz * (h2){hx0, hx0};   // v_pk_mul_f16
        h2 wB = hz * (h2){hx1, hx1};

        const float4* pA = sg4 + (srow + lxr) * CF4 + z0 * 3;
        const float4* pB = pA + CF4;
        float4 A0 = pA[0], A1 = pA[1], A2 = pA[2];
        float4 B0 = pB[0], B1 = pB[1], B2 = pB[2];

        float co[12];
        co[0]  = fdot2f(wA, bch2(A0.x), fdot2f(wB, bch2(B0.x), 0.0f));
        co[1]  = fdot2f(wA, bch2(A0.y), fdot2f(wB, bch2(B0.y), 0.0f));
        co[2]  = fdot2f(wA, bch2(A0.z), fdot2f(wB, bch2(B0.z), 0.0f));
        co[3]  = fdot2f(wA, bch2(A0.w), fdot2f(wB, bch2(B0.w), 0.0f));
        co[4]  = fdot2f(wA, bch2(A1.x), fdot2f(wB, bch2(B1.x), 0.0f));
        co[5]  = fdot2f(wA, bch2(A1.y), fdot2f(wB, bch2(B1.y), 0.0f));
        co[6]  = fdot2f(wA, bch2(A1.z), fdot2f(wB, bch2(B1.z), 0.0f));
        co[7]  = fdot2f(wA, bch2(A1.w), fdot2f(wB, bch2(B1.w), 0.0f));
        co[8]  = fdot2f(wA, bch2(A2.x), fdot2f(wB, bch2(B2.x), 0.0f));
        co[9]  = fdot2f(wA, bch2(A2.y), fdot2f(wB, bch2(B2.y), 0.0f));
        co[10] = fdot2f(wA, bch2(A2.z), fdot2f(wB, bch2(B2.z), 0.0f));
        co[11] = fdot2f(wA, bch2(A2.w), fdot2f(wB, bch2(B2.w), 0.0f));

        // apply
        const float r = rgb[0][j], gg = rgb[1][j], b = rgb[2][j];
        ov0p[j] = fmaf(co[0], r, fmaf(co[1],  gg, fmaf(co[2],  b, co[3])));
        ov1p[j] = fmaf(co[4], r, fmaf(co[5],  gg, fmaf(co[6],  b, co[7])));
        ov2p[j] = fmaf(co[8], r, fmaf(co[9],  gg, fmaf(co[10], b, co[11])));
    }

    // ---- coalesced float4 stores ----
    float* ob = out + (size_t)n * 3 * plane + (size_t)h * W + w0;
    *(float4*)(ob)             = ov0;
    *(float4*)(ob + plane)     = ov1;
    *(float4*)(ob + 2 * plane) = ov2;
}

extern "C" void kernel_launch(void* const* d_in, const int* in_sizes, int n_in,
                              void* d_out, int out_size, void* d_ws, size_t ws_size,
                              hipStream_t stream) {
    const float* grid_p = (const float*)d_in[0];
    const float* full_p = (const float*)d_in[1];
    const float* w1_p   = (const float*)d_in[2];
    const float* w3_p   = (const float*)d_in[3];
    const float* b3_p   = (const float*)d_in[4];
    const float* bias_p = (const float*)d_in[5];
    float* out_p = (float*)d_out;

    const size_t tbytes = (size_t)NIMG * 256 * CELLE * sizeof(h2);  // 540,672 B
    h2* table = (d_ws && ws_size >= tbytes) ? (h2*)d_ws : nullptr;

    if (table) {
        hipLaunchKernelGGL(pairgen, dim3(NIMG * NZ), dim3(256), 0, stream,
                           grid_p, table);
    }

    dim3 block(BX, BY, 1);
    dim3 grid_dim(W / TILE_W, H / BY, NIMG);
    hipLaunchKernelGGL(hdrnet_fused, grid_dim, block, 0, stream,
                       grid_p, full_p, w1_p, w3_p, b3_p, bias_p, table, out_p);
}

// Round 13
// 43.749 us; speedup vs baseline: 1.7905x; 1.1210x over previous
//
#include <hip/hip_runtime.h>

#define LEAK 0.01f

typedef float v2f __attribute__((ext_vector_type(2)));
typedef _Float16 h2 __attribute__((ext_vector_type(2)));

// Problem constants
constexpr int H = 1024, W = 1024, NIMG = 4;
constexpr int GC = 12, GD = 12, GH = 16, GW = 16;
constexpr int NZ = GD - 1;           // 11 z0 values (z-pairs)
constexpr int CELLE = NZ * GC;       // 132 half2 per (y,x) grid cell
constexpr int CF4 = 33;              // float4 chunks per cell (132 h2 = 528 B)

// Tiling: 256 threads (64x4), each thread does 4 pixels along x -> 256x4 tile
constexpr int PX = 4;
constexpr int BX = 64, BY = 4;
constexpr int TILE_W = BX * PX;      // 256
constexpr int XS = 6;                // x-cell footprint of a 256-wide tile
constexpr int SGN = BY * XS * CF4;   // 792 float4 of sgrid staging

// Lane-major fp32 image slab: pixel x <-> (j=(x-wb)&3, lanepos=(x-wb)>>2)
// layout simg[ch][row][j][IMJW], word = lanepos+1 (covers lanepos -1..64)
constexpr int IMROWS = BY + 2;       // 6 rows: hb-1 .. hb+4
constexpr int NCHUNK = 66;           // float4 chunks per (ch,row): c = -4 .. 259
constexpr int IMJW   = 68;           // padded j-plane width (66 used)
// size: 3*6*4*68*4 B = 19584 B

static __device__ __forceinline__ h2 bch2(float f) {
    return __builtin_bit_cast(h2, f);
}
static __device__ __forceinline__ float bcf(h2 v) {
    return __builtin_bit_cast(float, v);
}
// cvt_pkrtz returns __fp16x2; bit-cast to our h2 (_Float16x2) — same bits.
static __device__ __forceinline__ h2 pkrtz(float a, float b) {
    return __builtin_bit_cast(h2, __builtin_amdgcn_cvt_pkrtz(a, b));
}

static __device__ __forceinline__ float fdot2f(h2 a, h2 b, float c) {
#if __has_builtin(__builtin_amdgcn_fdot2)
    return __builtin_amdgcn_fdot2(a, b, c, false);
#else
    return (float)a.x * (float)b.x + (float)a.y * (float)b.y + c;
#endif
}

// ---- pre-kernel: build z-pair half2 table in ws ----
// table layout: [n][y*16+x][z0*12+c]  (132 half2 = 528 B contiguous per cell)
__global__ __launch_bounds__(256) void pairgen(const float* __restrict__ grid,
                                               h2* __restrict__ table) {
    const int n  = blockIdx.x / NZ;
    const int z0 = blockIdx.x % NZ;
    const int yx = threadIdx.x;      // 0..255, coalesced over lanes
    const float* src = grid + (size_t)n * GC * GD * GH * GW + yx;
    h2* dst = table + ((size_t)n * 256 + yx) * CELLE + z0 * GC;
    #pragma unroll
    for (int c = 0; c < GC; ++c) {
        float a = src[(c * GD + z0) * 256];
        float b = src[(c * GD + z0 + 1) * 256];
        dst[c] = pkrtz(a, b);
    }
}

__global__ __launch_bounds__(256) void hdrnet_fused(
    const float* __restrict__ grid,   // (N,12,12,16,16)
    const float* __restrict__ full,   // (N,3,H,W)
    const float* __restrict__ w1,     // (3,3,1,1)
    const float* __restrict__ w3,     // (3,3,3,3)
    const float* __restrict__ b3,     // (3)
    const float* __restrict__ bias,   // (1)
    const h2* __restrict__ table,     // pair table or nullptr
    float* __restrict__ out)          // (N,3,H,W)
{
    __shared__ __align__(16) float simg[3 * IMROWS * 4 * IMJW]; // 19584 B
    __shared__ __align__(16) h2 sgrid[BY * XS * CELLE];         // 12672 B

    const int n  = blockIdx.z;
    const int wb = blockIdx.x * TILE_W;
    const int hb = blockIdx.y * BY;

    const float scale = 15.0f / 1023.0f;
    const int xlo = (int)(wb * scale);

    const int tid = threadIdx.y * BX + threadIdx.x;
    const size_t plane = (size_t)H * W;
    const float* fn = full + (size_t)n * 3 * plane;

    // ---- issue table loads FIRST (oldest in vmcnt queue; latency hidden
    //      under the image staging loop) ----
    float4 tA[4], tB[4];
    const bool ttail = (tid < SGN - 768);   // 24 threads do a 4th element
    if (table) {
        const float4* tsrc = (const float4*)(table + (size_t)n * 256 * CELLE);
        #pragma unroll
        for (int it = 0; it < 3; ++it) {
            int e  = tid + 256 * it;
            int r  = e / (XS * CF4);
            int t2 = e - r * (XS * CF4);
            int lx = t2 / CF4, q = t2 - lx * CF4;
            int y0 = min((int)((float)(hb + r) * scale), GH - 2);
            int xi = min(xlo + lx, GW - 1);
            tA[it] = tsrc[(y0 * GW + xi) * CF4 + q];
            tB[it] = tsrc[((y0 + 1) * GW + xi) * CF4 + q];
        }
        if (ttail) {
            int e  = 768 + tid;
            int r  = e / (XS * CF4);
            int t2 = e - r * (XS * CF4);
            int lx = t2 / CF4, q = t2 - lx * CF4;
            int y0 = min((int)((float)(hb + r) * scale), GH - 2);
            int xi = min(xlo + lx, GW - 1);
            tA[3] = tsrc[(y0 * GW + xi) * CF4 + q];
            tB[3] = tsrc[((y0 + 1) * GW + xi) * CF4 + q];
        }
    }

    // ---- stage fullres tile into LDS, lane-major fp32 (2x ds_write2_b32) ----
    for (int e = tid; e < 3 * IMROWS * NCHUNK; e += BX * BY) {   // 1188 chunks
        int ch = e / (IMROWS * NCHUNK);
        int t  = e - ch * (IMROWS * NCHUNK);
        int r  = t / NCHUNK, m = t - r * NCHUNK;
        int yy = hb + r - 1;
        int gx = wb - 4 + 4 * m;
        float4 v = (float4){0.0f, 0.0f, 0.0f, 0.0f};
        if ((unsigned)yy < (unsigned)H && (unsigned)gx < (unsigned)W)
            v = *(const float4*)(fn + (size_t)ch * plane + (size_t)yy * W + gx);
        float* wp = &simg[((ch * IMROWS + r) * 4) * IMJW + m];
        wp[0 * IMJW] = v.x;
        wp[1 * IMJW] = v.y;
        wp[2 * IMJW] = v.z;
        wp[3 * IMJW] = v.w;
    }
    __syncthreads();   // image slab ready

    // ---- sgrid: y-lerp from registers, write LDS (conv below overlaps) ----
    if (table) {
        float4* sdst = (float4*)sgrid;
        #pragma unroll
        for (int it = 0; it < 4; ++it) {
            if (it == 3 && !ttail) break;
            int e = (it == 3) ? (768 + tid) : (tid + 256 * it);
            int r = e / (XS * CF4);
            float fy = (float)(hb + r) * scale;
            float ty = fy - (float)min((int)fy, GH - 2);
            _Float16 t1 = (_Float16)ty, t0 = (_Float16)(1.0f - ty);
            h2 w0v = (h2){t0, t0}, w1v = (h2){t1, t1};
            float4 A = tA[it], B = tB[it], R;
            R.x = bcf(bch2(A.x) * w0v + bch2(B.x) * w1v);
            R.y = bcf(bch2(A.y) * w0v + bch2(B.y) * w1v);
            R.z = bcf(bch2(A.z) * w0v + bch2(B.z) * w1v);
            R.w = bcf(bch2(A.w) * w0v + bch2(B.w) * w1v);
            sdst[e] = R;
        }
    } else {
        const float* gnn = grid + (size_t)n * GC * GD * GH * GW;
        for (int e = tid; e < BY * XS * CELLE; e += BX * BY) {
            int r  = e / (XS * CELLE);
            int t  = e - r * (XS * CELLE);
            int lx = t / CELLE, u = t - lx * CELLE;
            int z0 = u / GC, c = u - z0 * GC;
            float fy = (float)(hb + r) * scale;
            int y0 = min((int)fy, GH - 2);
            float ty = fy - (float)y0;
            int xi = min(xlo + lx, GW - 1);
            const float* gp = gnn + ((c * GD + z0) * GH + y0) * GW + xi;
            float a0 = gp[0],  a1 = gp[256];
            float b0 = gp[16], b1 = gp[272];
            sgrid[e] = pkrtz(fmaf(b0 - a0, ty, a0), fmaf(b1 - a1, ty, a1));
        }
    }

    const int h  = hb + threadIdx.y;
    const int w0 = wb + threadIdx.x * PX;

    // ---- weights to registers ----
    float w1c[3][3];
    #pragma unroll
    for (int o = 0; o < 3; ++o)
        #pragma unroll
        for (int i = 0; i < 3; ++i)
            w1c[o][i] = w1[o * 3 + i];
    const float biasv = bias[0];

    // ---- 3x3 conv over 3 ch for 4 pixels; rows via 4x ds_read2_b32,
    //      conflict-free, zero unpack (runs between barriers) ----
    v2f a3p[3][2];
    #pragma unroll
    for (int o = 0; o < 3; ++o) {
        float b = b3[o];
        a3p[o][0] = (v2f){b, b};
        a3p[o][1] = (v2f){b, b};
    }
    float rgb[3][PX];
    const int L = threadIdx.x;

    #pragma unroll
    for (int i = 0; i < 3; ++i) {
        #pragma unroll
        for (int dy = 0; dy < 3; ++dy) {
            const float* jp = &simg[((i * IMROWS + threadIdx.y + dy) * 4) * IMJW];
            float row[8];   // row[k] = pixel x = w0-1+k
            row[0] = jp[3 * IMJW + L];       // c=4L-1
            row[1] = jp[L + 1];              // c=4L
            row[2] = jp[1 * IMJW + L + 1];
            row[3] = jp[2 * IMJW + L + 1];
            row[4] = jp[3 * IMJW + L + 1];
            row[5] = jp[L + 2];              // c=4L+4
            row[6] = jp[1 * IMJW + L + 2];
            row[7] = jp[2 * IMJW + L + 2];
            if (dy == 1) {
                #pragma unroll
                for (int j = 0; j < PX; ++j) rgb[i][j] = row[1 + j];
            }
            #pragma unroll
            for (int o = 0; o < 3; ++o) {
                const float* kp = w3 + ((o * 3 + i) * 3 + dy) * 3;
                #pragma unroll
                for (int t = 0; t < 3; ++t) {
                    const float kt = kp[t];
                    v2f kv = (v2f){kt, kt};
                    a3p[o][0] = __builtin_elementwise_fma(
                        kv, (v2f){row[t], row[t + 1]}, a3p[o][0]);
                    a3p[o][1] = __builtin_elementwise_fma(
                        kv, (v2f){row[t + 2], row[t + 3]}, a3p[o][1]);
                }
            }
        }
    }
    __syncthreads();   // sgrid ready

    const int srow = threadIdx.y * XS;       // this thread-row's cell base
    const float4* sg4 = (const float4*)sgrid;

    float4 ov0, ov1, ov2;
    float* ov0p = &ov0.x; float* ov1p = &ov1.x; float* ov2p = &ov2.x;

    #pragma unroll
    for (int j = 0; j < PX; ++j) {
        // guide
        float gacc = 0.0f;
        #pragma unroll
        for (int o = 0; o < 3; ++o) {
            float x1 = fmaf(w1c[o][0], rgb[0][j],
                       fmaf(w1c[o][1], rgb[1][j], w1c[o][2] * rgb[2][j]));
            x1 = (x1 > 0.0f) ? x1 : LEAK * x1;
            float x3 = a3p[o][j >> 1][j & 1];
            x3 = (x3 > 0.0f) ? x3 : LEAK * x3;
            gacc += x1 + x3;
        }
        float g = fmaf(gacc, (1.0f / 3.0f), biasv);
        g = fminf(fmaxf(g, 0.0f), 1.0f);

        // slice coords (y already folded into LDS)
        float fx = (float)(w0 + j) * scale;
        int x0 = (int)fx;
        x0 = min(x0, GW - 2);
        float tx = fx - (float)x0;
        const int lxr = x0 - xlo;      // 0..4

        float fz = g * 11.0f;
        int z0 = (int)fz;
        z0 = min(z0, GD - 2);
        float tz = fz - (float)z0;
        h2 hz = pkrtz(1.0f - tz, tz);
        _Float16 hx0 = (_Float16)(1.0f - tx), hx1 = (_Float16)tx;
        h2 wA = hz * (h2){hx0, hx0};   // v_pk_mul_f16
        h2 wB = hz * (h2){hx1, hx1};

        const float4* pA = sg4 + (srow + lxr) * CF4 + z0 * 3;
        const float4* pB = pA + CF4;
        float4 A0 = pA[0], A1 = pA[1], A2 = pA[2];
        float4 B0 = pB[0], B1 = pB[1], B2 = pB[2];

        float co[12];
        co[0]  = fdot2f(wA, bch2(A0.x), fdot2f(wB, bch2(B0.x), 0.0f));
        co[1]  = fdot2f(wA, bch2(A0.y), fdot2f(wB, bch2(B0.y), 0.0f));
        co[2]  = fdot2f(wA, bch2(A0.z), fdot2f(wB, bch2(B0.z), 0.0f));
        co[3]  = fdot2f(wA, bch2(A0.w), fdot2f(wB, bch2(B0.w), 0.0f));
        co[4]  = fdot2f(wA, bch2(A1.x), fdot2f(wB, bch2(B1.x), 0.0f));
        co[5]  = fdot2f(wA, bch2(A1.y), fdot2f(wB, bch2(B1.y), 0.0f));
        co[6]  = fdot2f(wA, bch2(A1.z), fdot2f(wB, bch2(B1.z), 0.0f));
        co[7]  = fdot2f(wA, bch2(A1.w), fdot2f(wB, bch2(B1.w), 0.0f));
        co[8]  = fdot2f(wA, bch2(A2.x), fdot2f(wB, bch2(B2.x), 0.0f));
        co[9]  = fdot2f(wA, bch2(A2.y), fdot2f(wB, bch2(B2.y), 0.0f));
        co[10] = fdot2f(wA, bch2(A2.z), fdot2f(wB, bch2(B2.z), 0.0f));
        co[11] = fdot2f(wA, bch2(A2.w), fdot2f(wB, bch2(B2.w), 0.0f));

        // apply
        const float r = rgb[0][j], gg = rgb[1][j], b = rgb[2][j];
        ov0p[j] = fmaf(co[0], r, fmaf(co[1],  gg, fmaf(co[2],  b, co[3])));
        ov1p[j] = fmaf(co[4], r, fmaf(co[5],  gg, fmaf(co[6],  b, co[7])));
        ov2p[j] = fmaf(co[8], r, fmaf(co[9],  gg, fmaf(co[10], b, co[11])));
    }

    // ---- coalesced float4 stores ----
    float* ob = out + (size_t)n * 3 * plane + (size_t)h * W + w0;
    *(float4*)(ob)             = ov0;
    *(float4*)(ob + plane)     = ov1;
    *(float4*)(ob + 2 * plane) = ov2;
}

extern "C" void kernel_launch(void* const* d_in, const int* in_sizes, int n_in,
                              void* d_out, int out_size, void* d_ws, size_t ws_size,
                              hipStream_t stream) {
    const float* grid_p = (const float*)d_in[0];
    const float* full_p = (const float*)d_in[1];
    const float* w1_p   = (const float*)d_in[2];
    const float* w3_p   = (const float*)d_in[3];
    const float* b3_p   = (const float*)d_in[4];
    const float* bias_p = (const float*)d_in[5];
    float* out_p = (float*)d_out;

    const size_t tbytes = (size_t)NIMG * 256 * CELLE * sizeof(h2);  // 540,672 B
    h2* table = (d_ws && ws_size >= tbytes) ? (h2*)d_ws : nullptr;

    if (table) {
        hipLaunchKernelGGL(pairgen, dim3(NIMG * NZ), dim3(256), 0, stream,
                           grid_p, table);
    }

    dim3 block(BX, BY, 1);
    dim3 grid_dim(W / TILE_W, H / BY, NIMG);
    hipLaunchKernelGGL(hdrnet_fused, grid_dim, block, 0, stream,
                       grid_p, full_p, w1_p, w3_p, b3_p, bias_p, table, out_p);
}